// Round 1
// 503.757 us; speedup vs baseline: 1.0005x; 1.0005x over previous
//
#include <hip/hip_runtime.h>

#define N_NODES 10000
#define K_COLS 16
#define MEAN_NODES 625.0f

// ws layout (floats):
//   [0..15]                 : 1/gamma (written by prep_final)
//   [64 .. 64+40*32)        : per-block partials (40 blocks x {16 gamma, 16 colsum})
//   [2048 .. 2048+160000)   : Yn table [10000][16]  (written by yn_build)
//   [162048 .. 162048+10000): s_i = sum_k Yn[i,k]   (written by yn_build)
#define WS_PART_OFF 64
#define PREP_BLOCKS 40
#define WS_YN_OFF 2048
#define WS_S_OFF (WS_YN_OFF + N_NODES * K_COLS)

typedef float vf4 __attribute__((ext_vector_type(4)));

// force an already-uniform value into an SGPR so dependent loads take the
// scalar (SMEM/lgkmcnt) path instead of per-lane VMEM.
#define UNI(x) __builtin_amdgcn_readfirstlane(x)

// ---------------------------------------------------------------------------
// Kernel 1: per-block partial gamma/colsum. Block b: rows [b*250, b*250+250).
// ---------------------------------------------------------------------------
__global__ __launch_bounds__(256) void prep_partial(const float* __restrict__ Y,
                                                    const float* __restrict__ deg,
                                                    float* __restrict__ ws) {
    const int b = blockIdx.x;
    const int t = threadIdx.x;
    const int i = b * 250 + t;
    const bool valid = (t < 250);

    float y[K_COLS];
    float d = 0.f;
    if (valid) {
        d = deg[i];
        const float4* yp = (const float4*)(Y + (size_t)i * K_COLS);
        *(float4*)(y + 0)  = yp[0];
        *(float4*)(y + 4)  = yp[1];
        *(float4*)(y + 8)  = yp[2];
        *(float4*)(y + 12) = yp[3];
    } else {
#pragma unroll
        for (int k = 0; k < K_COLS; ++k) y[k] = 0.f;
    }

    float g[K_COLS], c[K_COLS];
#pragma unroll
    for (int k = 0; k < K_COLS; ++k) { g[k] = y[k] * d; c[k] = y[k]; }

#pragma unroll
    for (int k = 0; k < K_COLS; ++k) {
        for (int off = 32; off > 0; off >>= 1) {
            g[k] += __shfl_down(g[k], off);
            c[k] += __shfl_down(c[k], off);
        }
    }

    __shared__ float red[4][32];
    const int wave = t >> 6, lane = t & 63;
    if (lane == 0) {
#pragma unroll
        for (int k = 0; k < K_COLS; ++k) {
            red[wave][k] = g[k];
            red[wave][K_COLS + k] = c[k];
        }
    }
    __syncthreads();

    if (t < 32) {
        float v = red[0][t] + red[1][t] + red[2][t] + red[3][t];
        ws[WS_PART_OFF + b * 32 + t] = v;
    }
}

// ---------------------------------------------------------------------------
// Kernel 2: finalize — 1/gamma -> ws[0..15]; error_partition -> out[0].
// ---------------------------------------------------------------------------
__global__ __launch_bounds__(64) void prep_final(float* __restrict__ ws,
                                                 float* __restrict__ out) {
    const int t = threadIdx.x;
    if (t < 32) {
        float v = 0.f;
#pragma unroll
        for (int b = 0; b < PREP_BLOCKS; ++b) v += ws[WS_PART_OFF + b * 32 + t];
        if (t < 16) {
            ws[t] = 1.0f / v;   // rgamma
        } else {
            float dlt = v - MEAN_NODES;
            float sq = dlt * dlt;
            for (int off = 8; off > 0; off >>= 1) sq += __shfl_down(sq, off, 16);
            if (t == 16) out[0] = sq;
        }
    }
}

// ---------------------------------------------------------------------------
// Kernel 2b: materialize Yn[i][k] = Y[i][k] * rgamma[k] and s[i] = sum_k Yn.
// 680 KB of traffic — ~3 µs. Lets gap_main fetch per-row Yn through the
// scalar (s_load) path instead of LDS, which is what removes the VGPR spill.
// ---------------------------------------------------------------------------
__global__ __launch_bounds__(256) void yn_build(const float* __restrict__ Y,
                                                float* ws) {
    const int i = blockIdx.x * 256 + threadIdx.x;
    if (i >= N_NODES) return;

    float rg[K_COLS];
#pragma unroll
    for (int k = 0; k < K_COLS; ++k) rg[k] = ws[k];   // uniform -> s_load

    float y[K_COLS];
    const float4* yp = (const float4*)(Y + (size_t)i * K_COLS);
    *(float4*)(y + 0)  = yp[0];
    *(float4*)(y + 4)  = yp[1];
    *(float4*)(y + 8)  = yp[2];
    *(float4*)(y + 12) = yp[3];

    float yn[K_COLS];
    float s = 0.f;
#pragma unroll
    for (int k = 0; k < K_COLS; ++k) { yn[k] = y[k] * rg[k]; s += yn[k]; }

    float4* o = (float4*)(ws + WS_YN_OFF + (size_t)i * K_COLS);
    o[0] = *(float4*)(yn + 0);
    o[1] = *(float4*)(yn + 4);
    o[2] = *(float4*)(yn + 8);
    o[3] = *(float4*)(yn + 12);
    ws[WS_S_OFF + i] = s;
}

// ---------------------------------------------------------------------------
// Kernel 3 (hot), column-major accumulation:
//   error_cut = sum_j r_j - sum_{j,k} D[j,k]*Y[j,k],   D = A^T @ Yn,
//   r_j = sum_i A_ij * s_i,  s_i = sum_k Yn[i,k].
// v2: Yn_i / s_i are wave-uniform per row -> fetched via SGPRs (s_load from
// the precomputed ws table, address forced uniform with readfirstlane).
// Live VGPRs ~= d[64] + a/p[16] + addr ~= 96  (v1 had +32 for LDS-read yn
// copies -> spilled against the 128-reg cap of launch_bounds(256,4)).
// A stream: nt float4/lane, depth-2 prefetch, always in-bounds (rows ii+2,
// ii+3 <= 99), uniform row base + constant lane offset -> SALU-only addressing.
// yn rides lgkmcnt, A rides vmcnt -> independent counters, pipeline intact.
// grid = (10 j-tiles, 100 row-segments of 100 rows); 1000 blocks, 4/CU.
// ---------------------------------------------------------------------------
#define ROWS_PER_SEG 100
#define JT_WIDTH 1024

__device__ __forceinline__ vf4 ldA(const float* __restrict__ p, int lo) {
    return __builtin_nontemporal_load((const vf4*)(p + lo));
}

__device__ __forceinline__ void accum_row(const vf4 a, const float* __restrict__ ynp,
                                          const float si,
                                          float d[4][K_COLS], float r[4]) {
    const float av0 = a.x, av1 = a.y, av2 = a.z, av3 = a.w;
    r[0] += av0 * si; r[1] += av1 * si; r[2] += av2 * si; r[3] += av3 * si;
#pragma unroll
    for (int k = 0; k < K_COLS; ++k) {
        const float yk = ynp[k];          // uniform addr -> SGPR value
        d[0][k] += av0 * yk;
        d[1][k] += av1 * yk;
        d[2][k] += av2 * yk;
        d[3][k] += av3 * yk;
    }
}

__global__ __launch_bounds__(256, 4) void gap_main(const float* __restrict__ A,
                                                   const float* __restrict__ Y,
                                                   const float* __restrict__ ws,
                                                   float* __restrict__ out) {
    const int t = threadIdx.x;
    const int i0 = blockIdx.y * ROWS_PER_SEG;
    const int jblk = blockIdx.x * JT_WIDTH;
    const int lane_j = jblk + (t << 2);
    const bool jvalid = lane_j < N_NODES;
    // clamped lane offset: invalid lanes re-read the last valid float4
    const int lo = jvalid ? (t << 2) : (N_NODES - 4 - jblk);

    const float* __restrict__ yn_tab = ws + WS_YN_OFF;
    const float* __restrict__ s_tab  = ws + WS_S_OFF;

    float d[4][K_COLS];
    float r[4] = {0.f, 0.f, 0.f, 0.f};
#pragma unroll
    for (int jj = 0; jj < 4; ++jj)
#pragma unroll
        for (int k = 0; k < K_COLS; ++k) d[jj][k] = 0.f;

    const float* __restrict__ Arow = A + (size_t)i0 * N_NODES + jblk;

    // depth-2 pipeline, unroll 2 over rows, non-temporal A stream
    vf4 a0 = ldA(Arow, lo);
    vf4 a1 = ldA(Arow + N_NODES, lo);

#pragma unroll 1
    for (int ii = 0; ii < ROWS_PER_SEG - 2; ii += 2) {
        const float* pp = Arow + (size_t)(ii + 2) * N_NODES;   // rows ii+2, ii+3 <= 99: always in-bounds
        const vf4 p0 = ldA(pp, lo);
        const vf4 p1 = ldA(pp + N_NODES, lo);

        const int ro = UNI((i0 + ii) * K_COLS);
        const int rs = UNI(i0 + ii);
        accum_row(a0, yn_tab + ro,          s_tab[rs],     d, r);
        accum_row(a1, yn_tab + ro + K_COLS, s_tab[rs + 1], d, r);

        a0 = p0; a1 = p1;
    }
    {   // tail: rows 98, 99 already in flight
        const int ro = UNI((i0 + ROWS_PER_SEG - 2) * K_COLS);
        const int rs = UNI(i0 + ROWS_PER_SEG - 2);
        accum_row(a0, yn_tab + ro,          s_tab[rs],     d, r);
        accum_row(a1, yn_tab + ro + K_COLS, s_tab[rs + 1], d, r);
    }

    // epilogue: partial = sum_jj [ r_jj - sum_k d[jj][k]*Y[j0+jj][k] ]
    float partial = 0.f;
    if (jvalid) {
#pragma unroll
        for (int jj = 0; jj < 4; ++jj) {
            const float* yj = Y + (size_t)(lane_j + jj) * K_COLS;
            float yv[K_COLS];
            *(float4*)(yv + 0)  = *(const float4*)(yj + 0);
            *(float4*)(yv + 4)  = *(const float4*)(yj + 4);
            *(float4*)(yv + 8)  = *(const float4*)(yj + 8);
            *(float4*)(yv + 12) = *(const float4*)(yj + 12);
            float dot = 0.f;
#pragma unroll
            for (int k = 0; k < K_COLS; ++k) dot += d[jj][k] * yv[k];
            partial += r[jj] - dot;
        }
    }

    for (int off = 32; off > 0; off >>= 1) partial += __shfl_down(partial, off);
    __shared__ float wpart[4];
    const int wave = t >> 6, lane = t & 63;
    if (lane == 0) wpart[wave] = partial;
    __syncthreads();
    if (t == 0)
        atomicAdd(out, (wpart[0] + wpart[1]) + (wpart[2] + wpart[3]));
}

// ---------------------------------------------------------------------------
extern "C" void kernel_launch(void* const* d_in, const int* in_sizes, int n_in,
                              void* d_out, int out_size, void* d_ws, size_t ws_size,
                              hipStream_t stream) {
    const float* Y   = (const float*)d_in[0];   // [10000,16]
    const float* A   = (const float*)d_in[1];   // [10000,10000]
    const float* deg = (const float*)d_in[2];   // [10000,1]
    float* out = (float*)d_out;                 // scalar
    float* ws  = (float*)d_ws;

    hipLaunchKernelGGL(prep_partial, dim3(PREP_BLOCKS), dim3(256), 0, stream, Y, deg, ws);
    hipLaunchKernelGGL(prep_final, dim3(1), dim3(64), 0, stream, ws, out);
    hipLaunchKernelGGL(yn_build, dim3((N_NODES + 255) / 256), dim3(256), 0, stream, Y, ws);
    hipLaunchKernelGGL(gap_main, dim3(10, 100), dim3(256), 0, stream, A, Y, ws, out);
}

// Round 2
// 503.408 us; speedup vs baseline: 1.0012x; 1.0007x over previous
//
#include <hip/hip_runtime.h>

#define N_NODES 10000
#define K_COLS 16
#define MEAN_NODES 625.0f

// ws layout (floats):
//   [0..15]                 : 1/gamma (written by prep_final)
//   [64 .. 64+40*32)        : per-block partials (40 blocks x {16 gamma, 16 colsum})
//   [2048 .. 2048+160000)   : Yn table [10000][16]  (written by yn_build)
#define WS_PART_OFF 64
#define PREP_BLOCKS 40
#define WS_YN_OFF 2048

typedef float vf4 __attribute__((ext_vector_type(4)));

// force an already-uniform value into an SGPR so dependent loads take the
// scalar (SMEM/lgkmcnt) path instead of per-lane VMEM.
#define UNI(x) __builtin_amdgcn_readfirstlane(x)

// ---------------------------------------------------------------------------
// Kernel 1: per-block partial gamma/colsum. Block b: rows [b*250, b*250+250).
// ---------------------------------------------------------------------------
__global__ __launch_bounds__(256) void prep_partial(const float* __restrict__ Y,
                                                    const float* __restrict__ deg,
                                                    float* __restrict__ ws) {
    const int b = blockIdx.x;
    const int t = threadIdx.x;
    const int i = b * 250 + t;
    const bool valid = (t < 250);

    float y[K_COLS];
    float d = 0.f;
    if (valid) {
        d = deg[i];
        const float4* yp = (const float4*)(Y + (size_t)i * K_COLS);
        *(float4*)(y + 0)  = yp[0];
        *(float4*)(y + 4)  = yp[1];
        *(float4*)(y + 8)  = yp[2];
        *(float4*)(y + 12) = yp[3];
    } else {
#pragma unroll
        for (int k = 0; k < K_COLS; ++k) y[k] = 0.f;
    }

    float g[K_COLS], c[K_COLS];
#pragma unroll
    for (int k = 0; k < K_COLS; ++k) { g[k] = y[k] * d; c[k] = y[k]; }

#pragma unroll
    for (int k = 0; k < K_COLS; ++k) {
        for (int off = 32; off > 0; off >>= 1) {
            g[k] += __shfl_down(g[k], off);
            c[k] += __shfl_down(c[k], off);
        }
    }

    __shared__ float red[4][32];
    const int wave = t >> 6, lane = t & 63;
    if (lane == 0) {
#pragma unroll
        for (int k = 0; k < K_COLS; ++k) {
            red[wave][k] = g[k];
            red[wave][K_COLS + k] = c[k];
        }
    }
    __syncthreads();

    if (t < 32) {
        float v = red[0][t] + red[1][t] + red[2][t] + red[3][t];
        ws[WS_PART_OFF + b * 32 + t] = v;
    }
}

// ---------------------------------------------------------------------------
// Kernel 2: finalize — 1/gamma -> ws[0..15]; error_partition -> out[0].
// ---------------------------------------------------------------------------
__global__ __launch_bounds__(64) void prep_final(float* __restrict__ ws,
                                                 float* __restrict__ out) {
    const int t = threadIdx.x;
    if (t < 32) {
        float v = 0.f;
#pragma unroll
        for (int b = 0; b < PREP_BLOCKS; ++b) v += ws[WS_PART_OFF + b * 32 + t];
        if (t < 16) {
            ws[t] = 1.0f / v;   // rgamma
        } else {
            float dlt = v - MEAN_NODES;
            float sq = dlt * dlt;
            for (int off = 8; off > 0; off >>= 1) sq += __shfl_down(sq, off, 16);
            if (t == 16) out[0] = sq;
        }
    }
}

// ---------------------------------------------------------------------------
// Kernel 2b: materialize Yn[i][k] = Y[i][k] * rgamma[k] into ws.
// ---------------------------------------------------------------------------
__global__ __launch_bounds__(256) void yn_build(const float* __restrict__ Y,
                                                float* ws) {
    const int i = blockIdx.x * 256 + threadIdx.x;
    if (i >= N_NODES) return;

    float rg[K_COLS];
#pragma unroll
    for (int k = 0; k < K_COLS; ++k) rg[k] = ws[k];   // uniform -> s_load

    float y[K_COLS];
    const float4* yp = (const float4*)(Y + (size_t)i * K_COLS);
    *(float4*)(y + 0)  = yp[0];
    *(float4*)(y + 4)  = yp[1];
    *(float4*)(y + 8)  = yp[2];
    *(float4*)(y + 12) = yp[3];

    float yn[K_COLS];
#pragma unroll
    for (int k = 0; k < K_COLS; ++k) yn[k] = y[k] * rg[k];

    float4* o = (float4*)(ws + WS_YN_OFF + (size_t)i * K_COLS);
    o[0] = *(float4*)(yn + 0);
    o[1] = *(float4*)(yn + 4);
    o[2] = *(float4*)(yn + 8);
    o[3] = *(float4*)(yn + 12);
}

// ---------------------------------------------------------------------------
// Kernel 3 (hot), v3. Column-major accumulation into d[4][16] only:
//   D = A^T @ Yn;  partial_jj = sum_k d[jj][k] * (1 - Y[j,k])
// (the old r-term is algebraically sum_k d[jj][k] -> folded into epilogue,
// removing 4 FMAs/row and the s-table scalar stream).
// Latency: unroll 4 rows, depth-4 prefetch -> 4 nt-loads (64 B) in flight
// per wave steady state (v2 had 2), 64 KB/CU outstanding. Yn rides the
// scalar path (lgkmcnt), A rides vmcnt -> independent counters.
// VGPRs: d[64] + a[16] + p[16] + addr ~ 105 < 128 cap of (256,4); 1000
// blocks all co-resident at 4 blocks/CU.
// grid = (10 j-tiles x 1024 cols, 100 row-segments x 100 rows)
// ---------------------------------------------------------------------------
#define ROWS_PER_SEG 100
#define JT_WIDTH 1024

__device__ __forceinline__ vf4 ldA(const float* __restrict__ p, int lo) {
    return __builtin_nontemporal_load((const vf4*)(p + lo));
}

__device__ __forceinline__ void accum_row(const vf4 a, const float* __restrict__ ynp,
                                          float d[4][K_COLS]) {
    const float av0 = a.x, av1 = a.y, av2 = a.z, av3 = a.w;
#pragma unroll
    for (int k = 0; k < K_COLS; ++k) {
        const float yk = ynp[k];          // uniform addr -> SGPR value
        d[0][k] += av0 * yk;
        d[1][k] += av1 * yk;
        d[2][k] += av2 * yk;
        d[3][k] += av3 * yk;
    }
}

__global__ __launch_bounds__(256, 4) void gap_main(const float* __restrict__ A,
                                                   const float* __restrict__ Y,
                                                   const float* __restrict__ ws,
                                                   float* __restrict__ out) {
    const int t = threadIdx.x;
    const int i0 = blockIdx.y * ROWS_PER_SEG;
    const int jblk = blockIdx.x * JT_WIDTH;
    const int lane_j = jblk + (t << 2);
    const bool jvalid = lane_j < N_NODES;
    // clamped lane offset: invalid lanes re-read the last valid float4
    const int lo = jvalid ? (t << 2) : (N_NODES - 4 - jblk);

    // wave-uniform base of this segment's Yn rows (scalar path)
    const float* __restrict__ yn = ws + WS_YN_OFF + (size_t)UNI(i0) * K_COLS;

    float d[4][K_COLS];
#pragma unroll
    for (int jj = 0; jj < 4; ++jj)
#pragma unroll
        for (int k = 0; k < K_COLS; ++k) d[jj][k] = 0.f;

    const float* __restrict__ Ar = A + (size_t)i0 * N_NODES + jblk;

    // depth-4 pipeline, unroll 4 over rows, non-temporal A stream
    vf4 a0 = ldA(Ar, lo);
    vf4 a1 = ldA(Ar + (size_t)1 * N_NODES, lo);
    vf4 a2 = ldA(Ar + (size_t)2 * N_NODES, lo);
    vf4 a3 = ldA(Ar + (size_t)3 * N_NODES, lo);

#pragma unroll 1
    for (int ii = 0; ii < ROWS_PER_SEG - 4; ii += 4) {
        const float* pp = Ar + (size_t)(ii + 4) * N_NODES;   // rows ii+4..ii+7 <= 99
        const vf4 p0 = ldA(pp, lo);
        const vf4 p1 = ldA(pp + (size_t)1 * N_NODES, lo);
        const vf4 p2 = ldA(pp + (size_t)2 * N_NODES, lo);
        const vf4 p3 = ldA(pp + (size_t)3 * N_NODES, lo);

        const float* yr = yn + ii * K_COLS;
        accum_row(a0, yr,              d);
        accum_row(a1, yr + K_COLS,     d);
        accum_row(a2, yr + 2 * K_COLS, d);
        accum_row(a3, yr + 3 * K_COLS, d);

        a0 = p0; a1 = p1; a2 = p2; a3 = p3;
    }
    {   // tail: rows 96..99 already in flight
        const float* yr = yn + (ROWS_PER_SEG - 4) * K_COLS;
        accum_row(a0, yr,              d);
        accum_row(a1, yr + K_COLS,     d);
        accum_row(a2, yr + 2 * K_COLS, d);
        accum_row(a3, yr + 3 * K_COLS, d);
    }

    // epilogue: partial = sum_jj sum_k d[jj][k] * (1 - Y[j0+jj][k])
    float partial = 0.f;
    if (jvalid) {
#pragma unroll
        for (int jj = 0; jj < 4; ++jj) {
            const float* yj = Y + (size_t)(lane_j + jj) * K_COLS;
            float yv[K_COLS];
            *(float4*)(yv + 0)  = *(const float4*)(yj + 0);
            *(float4*)(yv + 4)  = *(const float4*)(yj + 4);
            *(float4*)(yv + 8)  = *(const float4*)(yj + 8);
            *(float4*)(yv + 12) = *(const float4*)(yj + 12);
            float dot = 0.f;
#pragma unroll
            for (int k = 0; k < K_COLS; ++k) dot += d[jj][k] * (1.0f - yv[k]);
            partial += dot;
        }
    }

    for (int off = 32; off > 0; off >>= 1) partial += __shfl_down(partial, off);
    __shared__ float wpart[4];
    const int wave = t >> 6, lane = t & 63;
    if (lane == 0) wpart[wave] = partial;
    __syncthreads();
    if (t == 0)
        atomicAdd(out, (wpart[0] + wpart[1]) + (wpart[2] + wpart[3]));
}

// ---------------------------------------------------------------------------
extern "C" void kernel_launch(void* const* d_in, const int* in_sizes, int n_in,
                              void* d_out, int out_size, void* d_ws, size_t ws_size,
                              hipStream_t stream) {
    const float* Y   = (const float*)d_in[0];   // [10000,16]
    const float* A   = (const float*)d_in[1];   // [10000,10000]
    const float* deg = (const float*)d_in[2];   // [10000,1]
    float* out = (float*)d_out;                 // scalar
    float* ws  = (float*)d_ws;

    hipLaunchKernelGGL(prep_partial, dim3(PREP_BLOCKS), dim3(256), 0, stream, Y, deg, ws);
    hipLaunchKernelGGL(prep_final, dim3(1), dim3(64), 0, stream, ws, out);
    hipLaunchKernelGGL(yn_build, dim3((N_NODES + 255) / 256), dim3(256), 0, stream, Y, ws);
    hipLaunchKernelGGL(gap_main, dim3(10, 100), dim3(256), 0, stream, A, Y, ws, out);
}